// Round 3
// baseline (139.241 us; speedup 1.0000x reference)
//
#include <hip/hip_runtime.h>

#define NB 32
#define CIN 64
#define TT 300
#define VV 25
#define NI 32
#define CO 128
#define TB 4
#define V4 (TB*VV)            // 100
#define NTILE 7               // ceil(112/16)
#define NBLK (NB*TT/TB)       // 2400
#define NBUCKET 64
#define EPSV 1e-5f
#define SCALEV 0.17677669529663687f   // 1/sqrt(32)
#define NRED (NB*TT*VV)       // 240000

using bf16x8 = __attribute__((ext_vector_type(8))) short;
using f32x4  = __attribute__((ext_vector_type(4))) float;
typedef unsigned short ushort_t;

__device__ __forceinline__ unsigned short f2bf(float f) {
    union { float f; unsigned u; } v; v.f = f;
    unsigned u = v.u;
    return (unsigned short)((u + 0x7fffu + ((u >> 16) & 1u)) >> 16);   // RNE
}
__device__ __forceinline__ unsigned pk2(float a, float b) {
    return (unsigned)f2bf(a) | ((unsigned)f2bf(b) << 16);
}

// ---------------------------------------------------------------------------
// K0: pre-swizzle weights into MFMA fragment order (bf16).
// twA/pwA: A-frags  A[i][c]  -> [((it*2+ks)*64 + lane)*8 + j]
// gwB:     B-frags  B[c][o]=gw[o][c] -> [((ot*2+ks)*64 + lane)*8 + j]
// ---------------------------------------------------------------------------
__global__ void agc_k0(const float* __restrict__ tw, const float* __restrict__ pw,
                       const float* __restrict__ gw,
                       ushort_t* __restrict__ twA, ushort_t* __restrict__ pwA,
                       ushort_t* __restrict__ gwB)
{
    int e = blockIdx.x*256 + threadIdx.x;      // 0..12287
    if (e >= 12288) return;
    int j = e & 7, l = (e >> 3) & 63, ks = (e >> 9) & 1, tile = e >> 10;
    int gg = l >> 4, n = l & 15;
    int c = ks*32 + gg*8 + j;
    if (tile < 2)      { int i = tile*16 + n;     twA[e]        = f2bf(tw[i*CIN + c]); }
    else if (tile < 4) { int i = (tile-2)*16 + n; pwA[e - 2048] = f2bf(pw[i*CIN + c]); }
    else               { int o = (tile-4)*16 + n; gwB[e - 4096] = f2bf(gw[o*CIN + c]); }
}

// ---------------------------------------------------------------------------
// K1: one block (4 waves, 256 thr) per 4 t-slices. All matmuls on MFMA.
// LDS map (bytes):
//   xT   [112][72] bf16      0 .. 16128
//   th   [112][40] bf16  16128 .. 25088   (overlaid by xs f32 [64][101] in P0)
//   phT  [112][40] bf16  25088 .. 34048
//   Pm   [112][40] bf16  34048 .. 43008
//   gT   [128][136] bf16 43008 .. 77824   (k-slot layout: [o][s*32+wl], pads 0)
//   red  [256] f32       77824 .. 78848
//   outS [4][128][28] f32    0 .. 57344   (overlay, live after B3 only)
// ---------------------------------------------------------------------------
__global__ __launch_bounds__(256, 2) void agc_k1(
    const float* __restrict__ x,
    const float* __restrict__ tb, const float* __restrict__ pb, const float* __restrict__ gb,
    const ushort_t* __restrict__ twA, const ushort_t* __restrict__ pwA,
    const ushort_t* __restrict__ gwB,
    float* __restrict__ out, float* __restrict__ bsum, float* __restrict__ bsq)
{
    __shared__ __align__(16) unsigned char lds[78848];
    ushort_t* xT  = (ushort_t*)lds;               // [112][72]
    ushort_t* th  = (ushort_t*)(lds + 16128);     // [112][40]
    ushort_t* phT = (ushort_t*)(lds + 25088);     // [112][40]
    ushort_t* Pm  = (ushort_t*)(lds + 34048);     // [112][40]
    ushort_t* gT  = (ushort_t*)(lds + 43008);     // [128][136]
    float* red_s  = (float*)(lds + 77824);        // [128]
    float* red_q  = (float*)(lds + 78336);        // [128]
    float* xs     = (float*)(lds + 16128);        // [64][101] overlay (dead after B1)
    float* outS   = (float*)lds;                  // [4][128][28] overlay (after B3)

    const int tid  = threadIdx.x;
    const int lane = tid & 63;
    const int wid  = tid >> 6;
    const int g    = lane >> 4;       // 0..3
    const int n16  = lane & 15;

    const int sl = ((blockIdx.x & 7) * (NBLK/8)) + (blockIdx.x >> 3);   // XCD swizzle
    const int b  = sl / (TT/TB);
    const int tb4 = sl - b*(TT/TB);   // 0..74
    const int t0 = tb4 * TB;

    // ---- P0: stage x slab (64 ch x 100 v) f32, zero red + gT pads ----
    const float4* gx = (const float4*)x + (size_t)b*120000 + (size_t)tb4*25;
    for (int e = tid; e < 1600; e += 256) {
        int c = e / 25, f4 = e - c*25;
        float4 v = gx[c*1875 + f4];
        float* p = &xs[c*101 + f4*4];
        p[0] = v.x; p[1] = v.y; p[2] = v.z; p[3] = v.w;
    }
    ((float*)(lds + 77824))[tid] = 0.f;           // red_s + red_q
    for (int e = tid; e < 512; e += 256) {        // gT k-pad slots -> 0
        int o = e >> 2, s = e & 3;
        ushort_t* p = &gT[o*136 + s*32 + 25];
        #pragma unroll
        for (int j = 0; j < 7; ++j) p[j] = 0;
    }
    __syncthreads();                              // B0

    // ---- transpose+convert: xT[v][c], rows 100..111 zero ----
    for (int e = tid; e < 112*64; e += 256) {
        int v = e >> 6, c = e & 63;
        float val = (v < V4) ? xs[c*101 + v] : 0.f;
        xT[v*72 + c] = f2bf(val);
    }
    __syncthreads();                              // B1

    // ---- P1: projections on MFMA ----
    bf16x8 xf[NTILE][2];
    #pragma unroll
    for (int vt = 0; vt < NTILE; ++vt)
        #pragma unroll
        for (int ks = 0; ks < 2; ++ks)
            xf[vt][ks] = *(const bf16x8*)&xT[(vt*16 + n16)*72 + ks*32 + g*8];

    auto do_proj = [&](const ushort_t* wA, const float* bias, ushort_t* dst) {
        #pragma unroll
        for (int it = 0; it < 2; ++it) {
            int i0 = it*16 + g*4;
            f32x4 binit = {bias[i0], bias[i0+1], bias[i0+2], bias[i0+3]};
            bf16x8 a0 = *(const bf16x8*)&wA[((it*2 + 0)*64 + lane)*8];
            bf16x8 a1 = *(const bf16x8*)&wA[((it*2 + 1)*64 + lane)*8];
            #pragma unroll
            for (int vt = 0; vt < NTILE; ++vt) {
                f32x4 acc = binit;
                acc = __builtin_amdgcn_mfma_f32_16x16x32_bf16(a0, xf[vt][0], acc, 0, 0, 0);
                acc = __builtin_amdgcn_mfma_f32_16x16x32_bf16(a1, xf[vt][1], acc, 0, 0, 0);
                // D(i, v): col v = vt*16+n16, rows i0..i0+3 -> dst[v][i0..] packed
                *(uint2*)&dst[(vt*16 + n16)*40 + i0] =
                    make_uint2(pk2(acc[0], acc[1]), pk2(acc[2], acc[3]));
            }
        }
    };
    auto do_g = [&](int ot) {
        int o = ot*16 + n16;
        float gbias = gb[o];
        bf16x8 b0 = *(const bf16x8*)&gwB[((ot*2 + 0)*64 + lane)*8];
        bf16x8 b1 = *(const bf16x8*)&gwB[((ot*2 + 1)*64 + lane)*8];
        #pragma unroll
        for (int vt = 0; vt < NTILE; ++vt) {
            f32x4 acc = {gbias, gbias, gbias, gbias};
            acc = __builtin_amdgcn_mfma_f32_16x16x32_bf16(xf[vt][0], b0, acc, 0, 0, 0);
            acc = __builtin_amdgcn_mfma_f32_16x16x32_bf16(xf[vt][1], b1, acc, 0, 0, 0);
            // D(v, o): rows v = vt*16+g*4+r, col o -> gT[o][(v/25)*32 + v%25]
            #pragma unroll
            for (int r = 0; r < 4; ++r) {
                int v = vt*16 + g*4 + r;
                if (v < V4) {
                    int s = (v*41) >> 10;       // v/25 for v<112
                    int wl = v - s*25;
                    gT[o*136 + s*32 + wl] = f2bf(acc[r]);
                }
            }
        }
    };

    if (wid == 0)      { do_proj(twA, tb, th);  do_g(0); }
    else if (wid == 1) { do_proj(pwA, pb, phT); do_g(1); }
    else if (wid == 2) { do_g(2); do_g(3); do_g(4); }
    else               { do_g(5); do_g(6); do_g(7); }
    __syncthreads();                              // B2

    // ---- P2: scores + softmax, wave s = wid handles slice s ----
    const int s = wid;
    {
        bf16x8 af0 = *(const bf16x8*)&th[(s*25 + n16)*40 + g*8];
        bf16x8 af1 = *(const bf16x8*)&th[(s*25 + 16 + n16)*40 + g*8];
        bf16x8 bf0 = *(const bf16x8*)&phT[(s*25 + n16)*40 + g*8];
        bf16x8 bf1 = *(const bf16x8*)&phT[(s*25 + 16 + n16)*40 + g*8];
        f32x4 z = {0.f, 0.f, 0.f, 0.f};
        f32x4 d00 = __builtin_amdgcn_mfma_f32_16x16x32_bf16(af0, bf0, z, 0, 0, 0);
        f32x4 d01 = __builtin_amdgcn_mfma_f32_16x16x32_bf16(af0, bf1, z, 0, 0, 0);
        f32x4 d10 = __builtin_amdgcn_mfma_f32_16x16x32_bf16(af1, bf0, z, 0, 0, 0);
        f32x4 d11 = __builtin_amdgcn_mfma_f32_16x16x32_bf16(af1, bf1, z, 0, 0, 0);
        const bool cval = (n16 <= 8);             // col 16+n16 < 25
        #pragma unroll
        for (int rt = 0; rt < 2; ++rt) {
            #pragma unroll
            for (int r = 0; r < 4; ++r) {
                float v0 = (rt ? d10[r] : d00[r]) * SCALEV;
                float v1 = cval ? (rt ? d11[r] : d01[r]) * SCALEV : -3.4e38f;
                float m = fmaxf(v0, v1);
                m = fmaxf(m, __shfl_xor(m, 1)); m = fmaxf(m, __shfl_xor(m, 2));
                m = fmaxf(m, __shfl_xor(m, 4)); m = fmaxf(m, __shfl_xor(m, 8));
                float e0 = __expf(v0 - m);
                float e1 = cval ? __expf(v1 - m) : 0.f;
                float sum = e0 + e1;
                sum += __shfl_xor(sum, 1); sum += __shfl_xor(sum, 2);
                sum += __shfl_xor(sum, 4); sum += __shfl_xor(sum, 8);
                float rinv = 1.f / sum;
                int vl = rt*16 + g*4 + r;
                if (vl < VV) {
                    Pm[(s*25 + vl)*40 + n16]      = f2bf(e0 * rinv);
                    Pm[(s*25 + vl)*40 + 16 + n16] = f2bf(e1 * rinv);  // zeros pad cols
                }
            }
        }
    }

    // ---- P3a: preload PV fragments (before overlay barrier) ----
    bf16x8 pa0 = *(const bf16x8*)&Pm[(s*25 + n16)*40 + g*8];
    bf16x8 pa1 = *(const bf16x8*)&Pm[(s*25 + 16 + n16)*40 + g*8];
    bf16x8 gB[8];
    #pragma unroll
    for (int ot = 0; ot < 8; ++ot)
        gB[ot] = *(const bf16x8*)&gT[(ot*16 + n16)*136 + s*32 + g*8];
    __syncthreads();                              // B3

    // ---- P3b: PV MFMAs -> outS staging + BN stats ----
    {
        f32x4 z = {0.f, 0.f, 0.f, 0.f};
        #pragma unroll
        for (int ot = 0; ot < 8; ++ot) {
            f32x4 e0 = __builtin_amdgcn_mfma_f32_16x16x32_bf16(pa0, gB[ot], z, 0, 0, 0);
            f32x4 e1 = __builtin_amdgcn_mfma_f32_16x16x32_bf16(pa1, gB[ot], z, 0, 0, 0);
            int o = ot*16 + n16;
            float* base = &outS[s*3584 + o*28];
            *(f32x4*)&base[g*4] = e0;             // rows g*4..g*4+3 (<16, valid)
            if (g < 2)       *(f32x4*)&base[16 + g*4] = e1;   // rows 16..23
            else if (g == 2) base[24] = e1[0];                 // row 24
            float sv = e0[0] + e0[1] + e0[2] + e0[3];
            float qv = e0[0]*e0[0] + e0[1]*e0[1] + e0[2]*e0[2] + e0[3]*e0[3];
            #pragma unroll
            for (int r = 0; r < 4; ++r) {
                int vl = 16 + g*4 + r;
                if (vl < VV) { sv += e1[r]; qv = fmaf(e1[r], e1[r], qv); }
            }
            sv += __shfl_xor(sv, 16); sv += __shfl_xor(sv, 32);
            qv += __shfl_xor(qv, 16); qv += __shfl_xor(qv, 32);
            if (lane < 16) {
                atomicAdd(&red_s[o], sv);
                atomicAdd(&red_q[o], qv);
            }
        }
    }
    __syncthreads();                              // B4

    // ---- P4: coalesced read-back + global store; fold stats to buckets ----
    for (int e = tid; e < 3200; e += 256) {
        int o = e / 25, v4 = e - o*25;
        int v0 = v4*4;
        float4 val;
        float tmp[4];
        #pragma unroll
        for (int j = 0; j < 4; ++j) {
            int v = v0 + j;
            int ss = (v*41) >> 10;
            int vl = v - ss*25;
            tmp[j] = outS[ss*3584 + o*28 + vl];
        }
        val.x = tmp[0]; val.y = tmp[1]; val.z = tmp[2]; val.w = tmp[3];
        ((float4*)out)[(size_t)(b*CO + o)*1875 + tb4*25 + v4] = val;
    }
    if (tid < CO) {
        int bkt = blockIdx.x & (NBUCKET-1);
        atomicAdd(&bsum[bkt*CO + tid], red_s[tid]);
        atomicAdd(&bsq[bkt*CO + tid],  red_q[tid]);
    }
}

// ---------------------------------------------------------------------------
// K2: fold buckets -> per-channel scale/shift  (1 block, 128 threads)
// ---------------------------------------------------------------------------
__global__ void agc_k2(const float* __restrict__ bsum, const float* __restrict__ bsq,
                       const float* __restrict__ gamma, const float* __restrict__ beta,
                       float* __restrict__ scl, float* __restrict__ shf)
{
    const int o = threadIdx.x;
    float s = 0.f, q = 0.f;
    for (int k = 0; k < NBUCKET; ++k) { s += bsum[k*CO + o]; q += bsq[k*CO + o]; }
    float mean = s / (float)NRED;
    float var  = q / (float)NRED - mean*mean;
    float rstd = rsqrtf(var + EPSV);
    float sc = gamma[o] * rstd;
    scl[o] = sc;
    shf[o] = beta[o] - mean * sc;
}

// ---------------------------------------------------------------------------
// K3: in-place normalize d_out, float4 coalesced
// ---------------------------------------------------------------------------
__global__ __launch_bounds__(256) void agc_k3(
    float* __restrict__ out, const float* __restrict__ scl, const float* __restrict__ shf)
{
    const int n4 = NB*CO*TT*VV/4;
    float4* p = (float4*)out;
    for (int i = blockIdx.x*blockDim.x + threadIdx.x; i < n4; i += gridDim.x*blockDim.x) {
        int ch = (i / (TT*VV/4)) & (CO-1);
        float4 v = p[i];
        float sc = scl[ch], sh = shf[ch];
        v.x = fmaf(v.x, sc, sh);
        v.y = fmaf(v.y, sc, sh);
        v.z = fmaf(v.z, sc, sh);
        v.w = fmaf(v.w, sc, sh);
        p[i] = v;
    }
}

extern "C" void kernel_launch(void* const* d_in, const int* in_sizes, int n_in,
                              void* d_out, int out_size, void* d_ws, size_t ws_size,
                              hipStream_t stream) {
    const float* x     = (const float*)d_in[0];
    const float* tw    = (const float*)d_in[1];
    const float* tbb   = (const float*)d_in[2];
    const float* pw    = (const float*)d_in[3];
    const float* pbb   = (const float*)d_in[4];
    const float* gw    = (const float*)d_in[5];
    const float* gbb   = (const float*)d_in[6];
    const float* gamma = (const float*)d_in[7];
    const float* beta  = (const float*)d_in[8];
    float* out = (float*)d_out;
    float* ws  = (float*)d_ws;
    float* bsum = ws;                         // [64][128]
    float* bsq  = ws + NBUCKET*CO;            // [64][128]
    float* scl  = ws + 2*NBUCKET*CO;          // [128]
    float* shf  = ws + 2*NBUCKET*CO + CO;     // [128]
    ushort_t* twA = (ushort_t*)(ws + 2*NBUCKET*CO + 2*CO);  // 2048 bf16
    ushort_t* pwA = twA + 2048;                              // 2048 bf16
    ushort_t* gwB = twA + 4096;                              // 8192 bf16

    hipMemsetAsync(d_ws, 0, (size_t)(2*NBUCKET*CO)*sizeof(float), stream);
    agc_k0<<<48, 256, 0, stream>>>(tw, pw, gw, twA, pwA, gwB);
    agc_k1<<<NBLK, 256, 0, stream>>>(x, tbb, pbb, gbb, twA, pwA, gwB, out, bsum, bsq);
    agc_k2<<<1, CO, 0, stream>>>(bsum, bsq, gamma, beta, scl, shf);
    agc_k3<<<2048, 256, 0, stream>>>(out, scl, shf);
}

// Round 5
// 106.771 us; speedup vs baseline: 1.3041x; 1.3041x over previous
//
#include <hip/hip_runtime.h>

#define NB 32
#define CIN 64
#define TT 300
#define VV 25
#define CO 128
#define NSLICE 9600
#define NBLK 2400
#define NBUCKET 64
#define EPSV 1e-5f
#define SCALEV 0.17677669529663687f   // 1/sqrt(32)
#define NRED (NB*TT*VV)               // 240000

using bf16x8 = __attribute__((ext_vector_type(8))) short;
using f32x4  = __attribute__((ext_vector_type(4))) float;
using f32x16 = __attribute__((ext_vector_type(16))) float;
typedef unsigned short ushort_t;

__device__ __forceinline__ unsigned short f2bf(float f) {
    union { float f; unsigned u; } v; v.f = f;
    unsigned u = v.u;
    return (unsigned short)((u + 0x7fffu + ((u >> 16) & 1u)) >> 16);   // RNE
}

// dst.lo16 = bf16(a), dst.hi16 = bf16(b)  (RNE)
__device__ __forceinline__ unsigned pkbf(float a, float b) {
    unsigned r;
    asm("v_cvt_pk_bf16_f32 %0, %1, %2" : "=v"(r) : "v"(a), "v"(b));
    return r;
}

// v_permlane32_swap_b32 a, b:
//   a' = [a.lanes0-31 | b.lanes0-31], b' = [a.lanes32-63 | b.lanes32-63]
// MUST model both results properly even when a==b (round-4 bug: "+v","+v"
// with identical input values coalesced to ONE register -> self-swap).
__device__ __forceinline__ void plswap(unsigned &a, unsigned &b) {
#if __has_builtin(__builtin_amdgcn_permlane32_swap)
    auto r = __builtin_amdgcn_permlane32_swap(a, b, false, false);
    a = r[0]; b = r[1];
#else
    unsigned a2, b2;
    asm("v_permlane32_swap_b32 %0, %1" : "=v"(a2), "=v"(b2) : "0"(a), "1"(b));
    a = a2; b = b2;
#endif
}
__device__ __forceinline__ float xhalf_sum(float x) {
    unsigned a = __float_as_uint(x), b = __float_as_uint(x);
    plswap(a, b);
    return __uint_as_float(a) + __uint_as_float(b);
}
__device__ __forceinline__ float xhalf_max(float x) {
    unsigned a = __float_as_uint(x), b = __float_as_uint(x);
    plswap(a, b);
    return fmaxf(__uint_as_float(a), __uint_as_float(b));
}
__device__ __forceinline__ f32x16 splat16(float v) {
    f32x16 r;
    #pragma unroll
    for (int i = 0; i < 16; ++i) r[i] = v;
    return r;
}

// D-tile (col = lane&31, row = (r&3)+8*(r>>2)+4*(lane>>5)) -> A/B fragments
// of a matrix whose lane-dim matches D's col and k dim = D's rows.
// frag[ks] k-elems = ks*16 + (lane>>5)*8 + j.
__device__ __forceinline__ void rearr(const f32x16& d, bf16x8& f0, bf16x8& f1) {
    unsigned u0 = pkbf(d[0],  d[1]),  u1 = pkbf(d[2],  d[3]);
    unsigned u2 = pkbf(d[4],  d[5]),  u3 = pkbf(d[6],  d[7]);
    unsigned u4 = pkbf(d[8],  d[9]),  u5 = pkbf(d[10], d[11]);
    unsigned u6 = pkbf(d[12], d[13]), u7 = pkbf(d[14], d[15]);
    plswap(u0, u2); plswap(u1, u3); plswap(u4, u6); plswap(u5, u7);
    union { unsigned u[4]; bf16x8 v; } c0, c1;
    c0.u[0] = u0; c0.u[1] = u1; c0.u[2] = u2; c0.u[3] = u3;
    c1.u[0] = u4; c1.u[1] = u5; c1.u[2] = u6; c1.u[3] = u7;
    f0 = c0.v; f1 = c1.v;
}

// ---------------------------------------------------------------------------
// K0: pre-swizzle weights into 32x32x16 fragment order + bias D-images.
// twA/pwA: A[i][c]  -> [(ks*64+l)*8+j],  c = ks*16+(l>>5)*8+j, i = l&31
// gwB:     B[c][o]  -> [((ot*4+ks)*64+l)*8+j], o = ot*32+(l&31)
// tbD/pbD: [l][r] = bias[(r&3)+8*(r>>2)+4*(l>>5)]
// ---------------------------------------------------------------------------
__global__ void agc_k0(const float* __restrict__ tw, const float* __restrict__ pw,
                       const float* __restrict__ gw,
                       const float* __restrict__ tb, const float* __restrict__ pb,
                       ushort_t* __restrict__ twA, ushort_t* __restrict__ pwA,
                       ushort_t* __restrict__ gwB,
                       float* __restrict__ tbD, float* __restrict__ pbD)
{
    int e = blockIdx.x*256 + threadIdx.x;
    if (e < 12288) {
        int j = e & 7, l = (e >> 3) & 63, ks = (e >> 9) & 3;
        int c = ks*16 + (l >> 5)*8 + j;
        int n = l & 31;
        int grp = e >> 11;          // 0: tw, 1: pw, 2..5: gw ot=grp-2
        if (grp == 0)      twA[e]        = f2bf(tw[n*CIN + c]);
        else if (grp == 1) pwA[e - 2048] = f2bf(pw[n*CIN + c]);
        else               gwB[e - 4096] = f2bf(gw[(grp - 2)*32*CIN + n*CIN + c]);
    } else if (e < 14336) {
        int e2 = e - 12288;
        int r = e2 & 15, l = (e2 >> 4) & 63;
        int i = (r & 3) + 8*(r >> 2) + 4*(l >> 5);
        if (e2 < 1024) tbD[e2]        = tb[i];
        else           pbD[e2 - 1024] = pb[i];
    }
}

// ---------------------------------------------------------------------------
// K1: ONE WAVE per (b,t) slice. No LDS, no barriers. All matmuls 32x32x16.
// ---------------------------------------------------------------------------
__global__ __launch_bounds__(256) void agc_k1(
    const float* __restrict__ x, const float* __restrict__ gb,
    const ushort_t* __restrict__ twA, const ushort_t* __restrict__ pwA,
    const ushort_t* __restrict__ gwB,
    const float* __restrict__ tbD, const float* __restrict__ pbD,
    float* __restrict__ out, float* __restrict__ bsum, float* __restrict__ bsq)
{
    const int tid  = threadIdx.x;
    const int lane = tid & 63;
    const int wid  = tid >> 6;
    const int l31  = lane & 31;
    const int h    = lane >> 5;

    const int blk = blockIdx.x;
    const int sl  = ((blk & 7) * (NBLK/8) + (blk >> 3)) * 4 + wid;   // XCD swizzle
    const int b   = sl / TT;
    const int t   = sl - b*TT;

    // ---- x fragments straight from global (A-role == B-role layout) ----
    // lane: v = l31 (clamped dup for v>=25), k-elems c = ks*16 + h*8 + j
    const float* xp = x + (size_t)b*CIN*TT*VV + (size_t)t*VV + (l31 < VV ? l31 : VV-1);
    bf16x8 xf[4];
    #pragma unroll
    for (int ks = 0; ks < 4; ++ks) {
        float v[8];
        #pragma unroll
        for (int j = 0; j < 8; ++j)
            v[j] = xp[(size_t)(ks*16 + h*8 + j)*TT*VV];
        union { unsigned u[4]; bf16x8 f; } c;
        c.u[0] = pkbf(v[0], v[1]); c.u[1] = pkbf(v[2], v[3]);
        c.u[2] = pkbf(v[4], v[5]); c.u[3] = pkbf(v[6], v[7]);
        xf[ks] = c.f;
    }

    // ---- th = tw@xT + tb, ph = pw@xT + pb  (D: col=v, rows=i) ----
    f32x16 th, ph;
    #pragma unroll
    for (int r = 0; r < 4; ++r) {
        f32x4 bb = ((const f32x4*)(tbD + lane*16))[r];
        th[4*r+0] = bb[0]; th[4*r+1] = bb[1]; th[4*r+2] = bb[2]; th[4*r+3] = bb[3];
        f32x4 pp = ((const f32x4*)(pbD + lane*16))[r];
        ph[4*r+0] = pp[0]; ph[4*r+1] = pp[1]; ph[4*r+2] = pp[2]; ph[4*r+3] = pp[3];
    }
    #pragma unroll
    for (int ks = 0; ks < 4; ++ks) {
        bf16x8 twf = *(const bf16x8*)(twA + (ks*64 + lane)*8);
        th = __builtin_amdgcn_mfma_f32_32x32x16_bf16(twf, xf[ks], th, 0, 0, 0);
        bf16x8 pwf = *(const bf16x8*)(pwA + (ks*64 + lane)*8);
        ph = __builtin_amdgcn_mfma_f32_32x32x16_bf16(pwf, xf[ks], ph, 0, 0, 0);
    }

    // ---- ST = ph^T_frag (A, rows w) x th_frag (B, cols v); k = i = 32 ----
    bf16x8 thf0, thf1, phf0, phf1;
    rearr(th, thf0, thf1);
    rearr(ph, phf0, phf1);
    f32x16 st = splat16(0.f);
    st = __builtin_amdgcn_mfma_f32_32x32x16_bf16(phf0, thf0, st, 0, 0, 0);
    st = __builtin_amdgcn_mfma_f32_32x32x16_bf16(phf1, thf1, st, 0, 0, 0);

    // ---- softmax over w (rows). valid: regs 0..11 always; reg 12 iff h==0 ----
    float s[13];
    #pragma unroll
    for (int r = 0; r < 13; ++r) s[r] = st[r] * SCALEV;
    float m = fmaxf(fmaxf(fmaxf(s[0], s[1]), fmaxf(s[2], s[3])),
                    fmaxf(fmaxf(s[4], s[5]), fmaxf(s[6], s[7])));
    m = fmaxf(m, fmaxf(fmaxf(s[8], s[9]), fmaxf(s[10], s[11])));
    float s12 = h ? -3.4e38f : s[12];
    m = fmaxf(m, s12);
    m = xhalf_max(m);
    f32x16 pd;
    #pragma unroll
    for (int r = 0; r < 12; ++r) pd[r] = __expf(s[r] - m);
    pd[12] = h ? 0.f : __expf(s[12] - m);
    pd[13] = 0.f; pd[14] = 0.f; pd[15] = 0.f;
    float sum = ((pd[0]+pd[1]) + (pd[2]+pd[3])) + ((pd[4]+pd[5]) + (pd[6]+pd[7]))
              + ((pd[8]+pd[9]) + (pd[10]+pd[11])) + pd[12];
    sum = xhalf_sum(sum);
    float rinv;
    asm("v_rcp_f32 %0, %1" : "=v"(rinv) : "v"(sum));
    #pragma unroll
    for (int r = 0; r < 13; ++r) pd[r] *= rinv;
    bf16x8 pf0, pf1;
    rearr(pd, pf0, pf1);   // A-frag: row v = l31, k = w

    // ---- per output tile: g-proj (JIT) + PV + store + stats ----
    const int bkt = blk & (NBUCKET-1);
    float* opb = out + (size_t)b*CO*TT*VV + (size_t)t*VV + 4*h;
    #pragma unroll
    for (int ot = 0; ot < 4; ++ot) {
        f32x16 gd = splat16(0.f);
        #pragma unroll
        for (int ks = 0; ks < 4; ++ks) {
            bf16x8 gf = *(const bf16x8*)(gwB + ((ot*4 + ks)*64 + lane)*8);
            gd = __builtin_amdgcn_mfma_f32_32x32x16_bf16(xf[ks], gf, gd, 0, 0, 0);
        }
        bf16x8 gf0, gf1;
        rearr(gd, gf0, gf1);            // B-frag: col o = l31, k = w
        // softmax rows sum to 1 -> fold g-bias into output init
        f32x16 od = splat16(gb[ot*32 + l31]);
        od = __builtin_amdgcn_mfma_f32_32x32x16_bf16(pf0, gf0, od, 0, 0, 0);
        od = __builtin_amdgcn_mfma_f32_32x32x16_bf16(pf1, gf1, od, 0, 0, 0);

        float* op = opb + (size_t)(ot*32 + l31)*TT*VV;
        float ss = 0.f, qq = 0.f;
        #pragma unroll
        for (int r = 0; r < 12; ++r) {
            int voff = (r & 3) + 8*(r >> 2);      // + 4h folded into opb
            op[voff] = od[r];
            ss += od[r]; qq = fmaf(od[r], od[r], qq);
        }
        if (!h) {                                  // v = 24 (reg 12, h==0 only)
            op[24] = od[12];
            ss += od[12]; qq = fmaf(od[12], od[12], qq);
        }
        ss = xhalf_sum(ss); qq = xhalf_sum(qq);
        if (lane < 32) {
            atomicAdd(&bsum[bkt*CO + ot*32 + l31], ss);
            atomicAdd(&bsq [bkt*CO + ot*32 + l31], qq);
        }
    }
}

// ---------------------------------------------------------------------------
// K2: fold buckets -> per-channel scale/shift  (1 block, 128 threads)
// ---------------------------------------------------------------------------
__global__ void agc_k2(const float* __restrict__ bsum, const float* __restrict__ bsq,
                       const float* __restrict__ gamma, const float* __restrict__ beta,
                       float* __restrict__ scl, float* __restrict__ shf)
{
    const int o = threadIdx.x;
    float s = 0.f, q = 0.f;
    for (int k = 0; k < NBUCKET; ++k) { s += bsum[k*CO + o]; q += bsq[k*CO + o]; }
    float mean = s / (float)NRED;
    float var  = q / (float)NRED - mean*mean;
    float rstd = rsqrtf(var + EPSV);
    float sc = gamma[o] * rstd;
    scl[o] = sc;
    shf[o] = beta[o] - mean * sc;
}

// ---------------------------------------------------------------------------
// K3: in-place normalize d_out, float4 coalesced (L3-resident)
// ---------------------------------------------------------------------------
__global__ __launch_bounds__(256) void agc_k3(
    float* __restrict__ out, const float* __restrict__ scl, const float* __restrict__ shf)
{
    const int n4 = NB*CO*TT*VV/4;
    float4* p = (float4*)out;
    for (int i = blockIdx.x*blockDim.x + threadIdx.x; i < n4; i += gridDim.x*blockDim.x) {
        int ch = (i / (TT*VV/4)) & (CO-1);
        float4 v = p[i];
        float sc = scl[ch], sh = shf[ch];
        v.x = fmaf(v.x, sc, sh);
        v.y = fmaf(v.y, sc, sh);
        v.z = fmaf(v.z, sc, sh);
        v.w = fmaf(v.w, sc, sh);
        p[i] = v;
    }
}

extern "C" void kernel_launch(void* const* d_in, const int* in_sizes, int n_in,
                              void* d_out, int out_size, void* d_ws, size_t ws_size,
                              hipStream_t stream) {
    const float* x     = (const float*)d_in[0];
    const float* tw    = (const float*)d_in[1];
    const float* tbb   = (const float*)d_in[2];
    const float* pw    = (const float*)d_in[3];
    const float* pbb   = (const float*)d_in[4];
    const float* gw    = (const float*)d_in[5];
    const float* gbb   = (const float*)d_in[6];
    const float* gamma = (const float*)d_in[7];
    const float* beta  = (const float*)d_in[8];
    float* out = (float*)d_out;
    float* ws  = (float*)d_ws;

    float* bsum = ws;                          // [64][128]
    float* bsq  = ws + NBUCKET*CO;             // [64][128]
    float* scl  = ws + 2*NBUCKET*CO;           // [128]
    float* shf  = ws + 2*NBUCKET*CO + CO;      // [128]
    ushort_t* twA = (ushort_t*)(ws + 2*NBUCKET*CO + 2*CO);   // 2048 bf16
    ushort_t* pwA = twA + 2048;                               // 2048 bf16
    ushort_t* gwB = twA + 4096;                               // 8192 bf16
    float* tbD = (float*)(gwB + 8192);                        // 1024 f32
    float* pbD = tbD + 1024;                                  // 1024 f32

    hipMemsetAsync(d_ws, 0, (size_t)(2*NBUCKET*CO)*sizeof(float), stream);
    agc_k0<<<56, 256, 0, stream>>>(tw, pw, gw, tbb, pbb, twA, pwA, gwB, tbD, pbD);
    agc_k1<<<NBLK, 256, 0, stream>>>(x, gbb, twA, pwA, gwB, tbD, pbD, out, bsum, bsq);
    agc_k2<<<1, CO, 0, stream>>>(bsum, bsq, gamma, beta, scl, shf);
    agc_k3<<<2048, 256, 0, stream>>>(out, scl, shf);
}

// Round 6
// 105.376 us; speedup vs baseline: 1.3214x; 1.0132x over previous
//
#include <hip/hip_runtime.h>

#define NB 32
#define CIN 64
#define TT 300
#define VV 25
#define CO 128
#define NBLK 2400             // blocks; 4 waves = 4 consecutive t-slices each
#define NBUCKET 64
#define EPSV 1e-5f
#define SCALEV 0.17677669529663687f   // 1/sqrt(32)
#define NRED (NB*TT*VV)               // 240000

using bf16x8 = __attribute__((ext_vector_type(8))) short;
using f32x4  = __attribute__((ext_vector_type(4))) float;
using f32x16 = __attribute__((ext_vector_type(16))) float;
typedef unsigned short ushort_t;

__device__ __forceinline__ unsigned short f2bf(float f) {
    union { float f; unsigned u; } v; v.f = f;
    unsigned u = v.u;
    return (unsigned short)((u + 0x7fffu + ((u >> 16) & 1u)) >> 16);   // RNE
}
__device__ __forceinline__ unsigned pkbf(float a, float b) {
    unsigned r;
    asm("v_cvt_pk_bf16_f32 %0, %1, %2" : "=v"(r) : "v"(a), "v"(b));
    return r;
}
// two-output permlane32_swap (round-4 lesson: must model BOTH results)
__device__ __forceinline__ void plswap(unsigned &a, unsigned &b) {
#if __has_builtin(__builtin_amdgcn_permlane32_swap)
    auto r = __builtin_amdgcn_permlane32_swap(a, b, false, false);
    a = r[0]; b = r[1];
#else
    unsigned a2, b2;
    asm("v_permlane32_swap_b32 %0, %1" : "=v"(a2), "=v"(b2) : "0"(a), "1"(b));
    a = a2; b = b2;
#endif
}
__device__ __forceinline__ float xhalf_sum(float x) {
    unsigned a = __float_as_uint(x), b = __float_as_uint(x);
    plswap(a, b);
    return __uint_as_float(a) + __uint_as_float(b);
}
__device__ __forceinline__ float xhalf_max(float x) {
    unsigned a = __float_as_uint(x), b = __float_as_uint(x);
    plswap(a, b);
    return fmaxf(__uint_as_float(a), __uint_as_float(b));
}
__device__ __forceinline__ f32x16 splat16(float v) {
    f32x16 r;
    #pragma unroll
    for (int i = 0; i < 16; ++i) r[i] = v;
    return r;
}
// D-tile (col=lane&31, row=(r&3)+8*(r>>2)+4*(lane>>5)) -> A/B frags, k=D rows
__device__ __forceinline__ void rearr(const f32x16& d, bf16x8& f0, bf16x8& f1) {
    unsigned u0 = pkbf(d[0],  d[1]),  u1 = pkbf(d[2],  d[3]);
    unsigned u2 = pkbf(d[4],  d[5]),  u3 = pkbf(d[6],  d[7]);
    unsigned u4 = pkbf(d[8],  d[9]),  u5 = pkbf(d[10], d[11]);
    unsigned u6 = pkbf(d[12], d[13]), u7 = pkbf(d[14], d[15]);
    plswap(u0, u2); plswap(u1, u3); plswap(u4, u6); plswap(u5, u7);
    union { unsigned u[4]; bf16x8 v; } c0, c1;
    c0.u[0] = u0; c0.u[1] = u1; c0.u[2] = u2; c0.u[3] = u3;
    c1.u[0] = u4; c1.u[1] = u5; c1.u[2] = u6; c1.u[3] = u7;
    f0 = c0.v; f1 = c1.v;
}

// ---------------------------------------------------------------------------
// K0: weights -> 32x32x16 fragment order + bias D-images (unchanged, verified)
// ---------------------------------------------------------------------------
__global__ void agc_k0(const float* __restrict__ tw, const float* __restrict__ pw,
                       const float* __restrict__ gw,
                       const float* __restrict__ tb, const float* __restrict__ pb,
                       ushort_t* __restrict__ twA, ushort_t* __restrict__ pwA,
                       ushort_t* __restrict__ gwB,
                       float* __restrict__ tbD, float* __restrict__ pbD)
{
    int e = blockIdx.x*256 + threadIdx.x;
    if (e < 12288) {
        int j = e & 7, l = (e >> 3) & 63, ks = (e >> 9) & 3;
        int c = ks*16 + (l >> 5)*8 + j;
        int n = l & 31;
        int grp = e >> 11;
        if (grp == 0)      twA[e]        = f2bf(tw[n*CIN + c]);
        else if (grp == 1) pwA[e - 2048] = f2bf(pw[n*CIN + c]);
        else               gwB[e - 4096] = f2bf(gw[(grp - 2)*32*CIN + n*CIN + c]);
    } else if (e < 14336) {
        int e2 = e - 12288;
        int r = e2 & 15, l = (e2 >> 4) & 63;
        int i = (r & 3) + 8*(r >> 2) + 4*(l >> 5);
        if (e2 < 1024) tbD[e2]        = tb[i];
        else           pbD[e2 - 1024] = pb[i];
    }
}

// ---------------------------------------------------------------------------
// K1: 4 waves/block, wave = one (b,t) slice on 32x32 MFMA (round-5 pipeline),
// block-level coalesced x staging + skewed LDS out staging + coalesced stores.
// LDS: [0,6400) f32 = xs[64][100] overlay outS[64][100]; [6400,6656) = red.
// ---------------------------------------------------------------------------
__global__ __launch_bounds__(256) void agc_k1(
    const float* __restrict__ x, const float* __restrict__ gb,
    const ushort_t* __restrict__ twA, const ushort_t* __restrict__ pwA,
    const ushort_t* __restrict__ gwB,
    const float* __restrict__ tbD, const float* __restrict__ pbD,
    float* __restrict__ out, float* __restrict__ bsum, float* __restrict__ bsq)
{
    __shared__ __align__(16) float lds[6656];
    float* xs   = lds;            // [64][100]
    float* outS = lds;            // [64][100] overlay (per o-half phase)
    float* red  = lds + 6400;     // [0..127] sum, [128..255] sumsq

    const int tid  = threadIdx.x;
    const int lane = tid & 63;
    const int wid  = tid >> 6;    // slice-in-block (t = t0 + wid)
    const int l31  = lane & 31;
    const int h    = lane >> 5;

    const int blk = blockIdx.x;
    const int grp = (blk & 7) * (NBLK/8) + (blk >> 3);   // XCD swizzle
    const int b   = grp / 75;
    const int j4  = grp - b*75;       // t0 = 4*j4

    red[tid] = 0.f;

    // ---- stage x slab: 64 ch x 100 v, coalesced float4 ----
    const float4* gx = (const float4*)x + (size_t)b*120000 + (size_t)j4*25;
    for (int e = tid; e < 1600; e += 256) {
        int c = e / 25, q = e - c*25;
        *(float4*)&xs[c*100 + q*4] = gx[c*1875 + q];
    }
    __syncthreads();                                     // B0

    // ---- x fragments from LDS (conflict-free b32) ----
    const int vcl  = l31 < VV ? l31 : VV-1;
    const int colx = wid*25 + vcl;
    bf16x8 xf[4];
    #pragma unroll
    for (int ks = 0; ks < 4; ++ks) {
        float v[8];
        #pragma unroll
        for (int jj = 0; jj < 8; ++jj)
            v[jj] = xs[(ks*16 + h*8 + jj)*100 + colx];
        union { unsigned u[4]; bf16x8 f; } c;
        c.u[0] = pkbf(v[0], v[1]); c.u[1] = pkbf(v[2], v[3]);
        c.u[2] = pkbf(v[4], v[5]); c.u[3] = pkbf(v[6], v[7]);
        xf[ks] = c.f;
    }
    __syncthreads();                                     // B1 (xs dead)

    // ---- th/ph projections ----
    f32x16 th, ph;
    #pragma unroll
    for (int r = 0; r < 4; ++r) {
        f32x4 bb = ((const f32x4*)(tbD + lane*16))[r];
        th[4*r+0] = bb[0]; th[4*r+1] = bb[1]; th[4*r+2] = bb[2]; th[4*r+3] = bb[3];
        f32x4 pp = ((const f32x4*)(pbD + lane*16))[r];
        ph[4*r+0] = pp[0]; ph[4*r+1] = pp[1]; ph[4*r+2] = pp[2]; ph[4*r+3] = pp[3];
    }
    #pragma unroll
    for (int ks = 0; ks < 4; ++ks) {
        bf16x8 twf = *(const bf16x8*)(twA + (ks*64 + lane)*8);
        th = __builtin_amdgcn_mfma_f32_32x32x16_bf16(twf, xf[ks], th, 0, 0, 0);
        bf16x8 pwf = *(const bf16x8*)(pwA + (ks*64 + lane)*8);
        ph = __builtin_amdgcn_mfma_f32_32x32x16_bf16(pwf, xf[ks], ph, 0, 0, 0);
    }

    // ---- scores ----
    bf16x8 thf0, thf1, phf0, phf1;
    rearr(th, thf0, thf1);
    rearr(ph, phf0, phf1);
    f32x16 st = splat16(0.f);
    st = __builtin_amdgcn_mfma_f32_32x32x16_bf16(phf0, thf0, st, 0, 0, 0);
    st = __builtin_amdgcn_mfma_f32_32x32x16_bf16(phf1, thf1, st, 0, 0, 0);

    // ---- softmax over w (rows 0..11 always, 12 iff h==0) ----
    float s[13];
    #pragma unroll
    for (int r = 0; r < 13; ++r) s[r] = st[r] * SCALEV;
    float m = fmaxf(fmaxf(fmaxf(s[0], s[1]), fmaxf(s[2], s[3])),
                    fmaxf(fmaxf(s[4], s[5]), fmaxf(s[6], s[7])));
    m = fmaxf(m, fmaxf(fmaxf(s[8], s[9]), fmaxf(s[10], s[11])));
    float s12 = h ? -3.4e38f : s[12];
    m = fmaxf(m, s12);
    m = xhalf_max(m);
    f32x16 pd;
    #pragma unroll
    for (int r = 0; r < 12; ++r) pd[r] = __expf(s[r] - m);
    pd[12] = h ? 0.f : __expf(s[12] - m);
    pd[13] = 0.f; pd[14] = 0.f; pd[15] = 0.f;
    float sum = ((pd[0]+pd[1]) + (pd[2]+pd[3])) + ((pd[4]+pd[5]) + (pd[6]+pd[7]))
              + ((pd[8]+pd[9]) + (pd[10]+pd[11])) + pd[12];
    sum = xhalf_sum(sum);
    float rinv;
    asm("v_rcp_f32 %0, %1" : "=v"(rinv) : "v"(sum));
    #pragma unroll
    for (int r = 0; r < 13; ++r) pd[r] *= rinv;
    bf16x8 pf0, pf1;
    rearr(pd, pf0, pf1);

    const int sv0 = wid*25 + 4*h;     // sv base for r<12 writes

    // ---- one output tile: g-proj + PV + skewed LDS stage + stats ----
    auto process_ot = [&](int ot) {
        f32x16 gd = splat16(0.f);
        #pragma unroll
        for (int ks = 0; ks < 4; ++ks) {
            bf16x8 gf = *(const bf16x8*)(gwB + ((ot*4 + ks)*64 + lane)*8);
            gd = __builtin_amdgcn_mfma_f32_32x32x16_bf16(xf[ks], gf, gd, 0, 0, 0);
        }
        bf16x8 gf0, gf1;
        rearr(gd, gf0, gf1);
        f32x16 od = splat16(gb[ot*32 + l31]);
        od = __builtin_amdgcn_mfma_f32_32x32x16_bf16(pf0, gf0, od, 0, 0, 0);
        od = __builtin_amdgcn_mfma_f32_32x32x16_bf16(pf1, gf1, od, 0, 0, 0);

        const int o_loc = (ot & 1)*32 + l31;   // row in phase buffer
        const int base  = o_loc*100;
        float ss = 0.f, qq = 0.f;
        #pragma unroll
        for (int r = 0; r < 12; ++r) {
            int sv = sv0 + (r & 3) + 8*(r >> 2);
            int u  = (sv >> 1) + o_loc;
            if (u >= 50) u -= 50;
            if (u >= 50) u -= 50;
            outS[base + u*2 + (sv & 1)] = od[r];
            ss += od[r]; qq = fmaf(od[r], od[r], qq);
        }
        if (!h) {
            int sv = wid*25 + 24;
            int u  = (sv >> 1) + o_loc;
            if (u >= 50) u -= 50;
            if (u >= 50) u -= 50;
            outS[base + u*2 + (sv & 1)] = od[12];
            ss += od[12]; qq = fmaf(od[12], od[12], qq);
        }
        ss = xhalf_sum(ss); qq = xhalf_sum(qq);
        if (lane < 32) {
            atomicAdd(&red[ot*32 + l31], ss);
            atomicAdd(&red[128 + ot*32 + l31], qq);
        }
    };

    // readback: inverse skew, b64 LDS read, coalesced float2 global store
    auto readback = [&](int p) {
        float2* o2 = (float2*)out;
        for (int e = tid; e < 3200; e += 256) {
            int ol = e / 50, q2 = e - ol*50;
            int u = q2 + ol;
            if (u >= 50) u -= 50;
            if (u >= 50) u -= 50;
            float2 v = *(float2*)&outS[ol*100 + u*2];
            o2[(size_t)(b*CO + p*64 + ol)*3750 + (size_t)j4*50 + q2] = v;
        }
    };

    process_ot(0); process_ot(1);
    __syncthreads();                                     // B2
    readback(0);
    __syncthreads();                                     // B3
    process_ot(2); process_ot(3);
    __syncthreads();                                     // B4
    readback(1);
    if (tid < CO) {
        int bkt = blk & (NBUCKET-1);
        atomicAdd(&bsum[bkt*CO + tid], red[tid]);
        atomicAdd(&bsq [bkt*CO + tid], red[128 + tid]);
    }
}

// ---------------------------------------------------------------------------
// K2: fold buckets -> per-channel scale/shift
// ---------------------------------------------------------------------------
__global__ void agc_k2(const float* __restrict__ bsum, const float* __restrict__ bsq,
                       const float* __restrict__ gamma, const float* __restrict__ beta,
                       float* __restrict__ scl, float* __restrict__ shf)
{
    const int o = threadIdx.x;
    float s = 0.f, q = 0.f;
    #pragma unroll 8
    for (int k = 0; k < NBUCKET; ++k) { s += bsum[k*CO + o]; q += bsq[k*CO + o]; }
    float mean = s / (float)NRED;
    float var  = q / (float)NRED - mean*mean;
    float rstd = rsqrtf(var + EPSV);
    float sc = gamma[o] * rstd;
    scl[o] = sc;
    shf[o] = beta[o] - mean * sc;
}

// ---------------------------------------------------------------------------
// K3: in-place normalize d_out, float4 coalesced (L3-resident)
// ---------------------------------------------------------------------------
__global__ __launch_bounds__(256) void agc_k3(
    float* __restrict__ out, const float* __restrict__ scl, const float* __restrict__ shf)
{
    const int n4 = NB*CO*TT*VV/4;
    float4* p = (float4*)out;
    for (int i = blockIdx.x*blockDim.x + threadIdx.x; i < n4; i += gridDim.x*blockDim.x) {
        int ch = (i / (TT*VV/4)) & (CO-1);
        float4 v = p[i];
        float sc = scl[ch], sh = shf[ch];
        v.x = fmaf(v.x, sc, sh);
        v.y = fmaf(v.y, sc, sh);
        v.z = fmaf(v.z, sc, sh);
        v.w = fmaf(v.w, sc, sh);
        p[i] = v;
    }
}

extern "C" void kernel_launch(void* const* d_in, const int* in_sizes, int n_in,
                              void* d_out, int out_size, void* d_ws, size_t ws_size,
                              hipStream_t stream) {
    const float* x     = (const float*)d_in[0];
    const float* tw    = (const float*)d_in[1];
    const float* tbb   = (const float*)d_in[2];
    const float* pw    = (const float*)d_in[3];
    const float* pbb   = (const float*)d_in[4];
    const float* gw    = (const float*)d_in[5];
    const float* gbb   = (const float*)d_in[6];
    const float* gamma = (const float*)d_in[7];
    const float* beta  = (const float*)d_in[8];
    float* out = (float*)d_out;
    float* ws  = (float*)d_ws;

    float* bsum = ws;                          // [64][128]
    float* bsq  = ws + NBUCKET*CO;             // [64][128]
    float* scl  = ws + 2*NBUCKET*CO;           // [128]
    float* shf  = ws + 2*NBUCKET*CO + CO;      // [128]
    ushort_t* twA = (ushort_t*)(ws + 2*NBUCKET*CO + 2*CO);   // 2048 bf16
    ushort_t* pwA = twA + 2048;                               // 2048 bf16
    ushort_t* gwB = twA + 4096;                               // 8192 bf16
    float* tbD = (float*)(gwB + 8192);                        // 1024 f32
    float* pbD = tbD + 1024;                                  // 1024 f32

    hipMemsetAsync(d_ws, 0, (size_t)(2*NBUCKET*CO)*sizeof(float), stream);
    agc_k0<<<56, 256, 0, stream>>>(tw, pw, gw, tbb, pbb, twA, pwA, gwB, tbD, pbD);
    agc_k1<<<NBLK, 256, 0, stream>>>(x, gbb, twA, pwA, gwB, tbD, pbD, out, bsum, bsq);
    agc_k2<<<1, CO, 0, stream>>>(bsum, bsq, gamma, beta, scl, shf);
    agc_k3<<<2048, 256, 0, stream>>>(out, scl, shf);
}